// Round 1
// 264.243 us; speedup vs baseline: 1.1291x; 1.1291x over previous
//
#include <hip/hip_runtime.h>
#include <hip/hip_bf16.h>
#include <stdint.h>

// GraphSAGE 2-layer encoder — atomic-free bucketed CSR build + MFMA layers.
// R12: exploit linearity of mean aggregation in layer2:
//   pre2:   g = h @ W2_l   (bf16 [N,64] — dense GEMM, sequential)
//   layer2: out = mean(g[src]) + h @ W2_r + b2
// gather row shrinks 256B -> 128B (working set 25.6 -> 12.8 MB).
// Also: x converted to bf16 once (convert_x) so layer1 gathers 128B rows
// regardless of input dtype; layer1 f32 gather path removed.
// xb and g share one ws region (xb dead before pre2 runs).

typedef unsigned short u16;
typedef __attribute__((ext_vector_type(8))) short short8;   // bf16x8 A/B frag
typedef __attribute__((ext_vector_type(4))) float f32x4;    // fp32x4 C/D frag

#define BSHIFT 9
#define BSIZE  512          // nodes per bucket
#define CHUNK  8192         // edges per partition block
#define NCP    256          // padded chunks-per-bucket stride (nchunk <= 256)

__device__ __forceinline__ float bf2f(u16 v) { return __uint_as_float(((uint32_t)v) << 16); }
__device__ __forceinline__ float bfu_lo(uint32_t u) { return __uint_as_float(u << 16); }
__device__ __forceinline__ float bfu_hi(uint32_t u) { return __uint_as_float(u & 0xffff0000u); }
__device__ __forceinline__ u16 f2bf(float f) {
    uint32_t u = __float_as_uint(f);
    return (u16)((u + 0x7fffu + ((u >> 16) & 1u)) >> 16);
}

// ---------------- probe: dtype flags ----------------
__global__ __launch_bounds__(256) void probe_k(
    const void* x, const void* w1l, const void* w1r, const void* b1,
    const void* w2l, const void* w2r, const void* b2, const void* ei,
    int* __restrict__ flags, int ne,
    int c0, int c1, int c2, int c3, int c4, int c5, int c6) {
    __shared__ int cs_s[8];
    int tid = threadIdx.x, a = tid >> 5, lane = tid & 31;
    if (tid < 8) cs_s[tid] = 0;
    __syncthreads();
    if (a < 7) {
        const void* ptrs[7] = {x, w1l, w1r, b1, w2l, w2r, b2};
        int cs[7] = {c0, c1, c2, c3, c4, c5, c6};
        int C = cs[a];
        int stride = C / 32; if (stride < 1) stride = 1;
        long long i = (long long)lane * stride;
        if (i > C - 1) i = C - 1;
        i &= ~1LL;
        u16 v = ((const u16*)ptrs[a])[i];
        int e = (v >> 7) & 0xFF;
        int sane = ((e >= 0x50 && e <= 0x97) || v == 0) ? 1 : 0;
        atomicAdd(&cs_s[a], sane);
    } else {
        long long n32 = 2LL * ne;
        long long stride = n32 / 32; if (stride < 1) stride = 1;
        long long i = (long long)lane * stride; i |= 1;
        if (i >= n32) i = 1;
        int wv = ((const int*)ei)[i];
        atomicAdd(&cs_s[7], wv != 0 ? 1 : 0);
    }
    __syncthreads();
    if (tid < 7) flags[tid] = (cs_s[tid] >= 24) ? 1 : 0;
    if (tid == 7) flags[7] = (cs_s[7] == 0) ? 1 : 0;
}

// ---------------- x -> bf16 (only if x is f32) ----------------
__global__ __launch_bounds__(256) void convert_x(
    const void* __restrict__ x, u16* __restrict__ xb,
    const int* __restrict__ flags, int n4) {
    if (flags[0]) return;   // x already bf16 — layer1 reads it directly
    int i = blockIdx.x * 256 + threadIdx.x;
    if (i < n4) {
        float4 f = ((const float4*)x)[i];
        *(ushort4*)&xb[(size_t)i * 4] =
            make_ushort4(f2bf(f.x), f2bf(f.y), f2bf(f.z), f2bf(f.w));
    }
}

// ---------------- per-chunk bucket histogram (no global atomics) ----------
__global__ __launch_bounds__(512) void count_chunks(
    const void* __restrict__ ei, int* __restrict__ hist2d,
    const int* __restrict__ flags, int nn, int ne, int nb) {
    __shared__ int hist[512];
    int tid = threadIdx.x;
    hist[tid] = 0;
    __syncthreads();
    int e64 = flags[7];
    int base = blockIdx.x * CHUNK;
#pragma unroll
    for (int j = 0; j < 16; j++) {
        int e = base + j * 512 + tid;
        if (e < ne) {
            int dst = e64 ? (int)((const long long*)ei)[(size_t)ne + e]
                          : ((const int*)ei)[(size_t)ne + e];
            if ((unsigned)dst < (unsigned)nn) atomicAdd(&hist[dst >> BSHIFT], 1);
        }
    }
    __syncthreads();
    for (int b = tid; b < nb; b += 512)
        hist2d[b * NCP + blockIdx.x] = hist[b];
}

// ---------------- per-bucket scan over chunks ----------------
__global__ __launch_bounds__(256) void scan2d(
    const int* __restrict__ hist2d, int* __restrict__ base2d,
    int* __restrict__ btot, int nchunk) {
    __shared__ int t0[256];
    int b = blockIdx.x, tid = threadIdx.x;
    int v = (tid < nchunk) ? hist2d[b * NCP + tid] : 0;
    t0[tid] = v;
    __syncthreads();
    for (int d = 1; d < 256; d <<= 1) {
        int t = (tid >= d) ? t0[tid - d] : 0;
        __syncthreads();
        t0[tid] += t;
        __syncthreads();
    }
    if (tid < nchunk) base2d[b * NCP + tid] = t0[tid] - v;
    if (tid == 255) btot[b] = t0[255];
}

// ---------------- bucket scan ----------------
__global__ __launch_bounds__(512) void scan_buckets(
    const int* __restrict__ btot, int* __restrict__ bo, int nb) {
    __shared__ int t0[512];
    int tid = threadIdx.x;
    int v = (tid < nb) ? btot[tid] : 0;
    t0[tid] = v;
    __syncthreads();
    for (int d = 1; d < 512; d <<= 1) {
        int t = (tid >= d) ? t0[tid - d] : 0;
        __syncthreads();
        t0[tid] += t;
        __syncthreads();
    }
    if (tid < nb) bo[tid] = t0[tid] - v;
    if (tid == 511) bo[nb] = t0[511];
}

// ---------------- partition: bucket-grouped packed edges, atomic-free -----
__global__ __launch_bounds__(512) void partition_k(
    const void* __restrict__ ei, const int* __restrict__ bo,
    const int* __restrict__ base2d,
    unsigned* __restrict__ ep, const int* __restrict__ flags,
    int nn, int ne, int nb) {
    __shared__ unsigned stage[CHUNK];    // 32 KB
    __shared__ u16 ab[CHUNK];            // 16 KB
    __shared__ int hist[512], incl[512], exl[512], gbase[512], lcur[512];
    int tid = threadIdx.x;
    int base = blockIdx.x * CHUNK;
    hist[tid] = 0;
    __syncthreads();
    int e64 = flags[7];
    unsigned pk[16]; int bk[16];
#pragma unroll
    for (int j = 0; j < 16; j++) {
        int e = base + j * 512 + tid;
        bk[j] = -1;
        pk[j] = 0;
        if (e < ne) {
            int src, dst;
            if (e64) {
                src = (int)((const long long*)ei)[e];
                dst = (int)((const long long*)ei)[(size_t)ne + e];
            } else {
                src = ((const int*)ei)[e];
                dst = ((const int*)ei)[(size_t)ne + e];
            }
            if ((unsigned)dst < (unsigned)nn) {
                if ((unsigned)src >= (unsigned)nn) src = 0;
                bk[j] = dst >> BSHIFT;
                pk[j] = (unsigned)src | ((unsigned)(dst & (BSIZE - 1)) << 17);
                atomicAdd(&hist[bk[j]], 1);
            }
        }
    }
    __syncthreads();
    incl[tid] = hist[tid];
    __syncthreads();
    for (int d = 1; d < 512; d <<= 1) {
        int t = (tid >= d) ? incl[tid - d] : 0;
        __syncthreads();
        incl[tid] += t;
        __syncthreads();
    }
    int ex = incl[tid] - hist[tid];
    exl[tid] = ex;
    lcur[tid] = ex;
    gbase[tid] = (tid < nb) ? (bo[tid] + base2d[tid * NCP + blockIdx.x]) : 0;
    __syncthreads();
#pragma unroll
    for (int j = 0; j < 16; j++) {
        if (bk[j] >= 0) {
            int r = atomicAdd(&lcur[bk[j]], 1);
            stage[r] = pk[j];
            ab[r] = (u16)bk[j];
        }
    }
    __syncthreads();
    int tot = incl[511];
    for (int j = tid; j < tot; j += 512) {
        int b = ab[j];
        ep[gbase[b] + (j - exl[b])] = stage[j];
    }
}

// ---------------- per-bucket CSR finalize ----------------
__global__ __launch_bounds__(512) void csr_fill2(
    const unsigned* __restrict__ ep, const int* __restrict__ bo,
    int* __restrict__ off, int* __restrict__ cnt, int* __restrict__ esrc,
    int nn) {
    __shared__ int hist[BSIZE], incl[BSIZE], lcur[BSIZE];
    int b = blockIdx.x;
    int beg = bo[b], end = bo[b + 1];
    int tid = threadIdx.x;
    hist[tid] = 0;
    __syncthreads();
    for (int j = beg + tid; j < end; j += 512)
        atomicAdd(&hist[(ep[j] >> 17) & (BSIZE - 1)], 1);
    __syncthreads();
    incl[tid] = hist[tid];
    __syncthreads();
    for (int d = 1; d < 512; d <<= 1) {
        int t = (tid >= d) ? incl[tid - d] : 0;
        __syncthreads();
        incl[tid] += t;
        __syncthreads();
    }
    int ex = beg + incl[tid] - hist[tid];
    lcur[tid] = ex;
    int node = b * BSIZE + tid;
    if (node < nn) { off[node] = ex; cnt[node] = hist[tid]; }
    __syncthreads();
    for (int j = beg + tid; j < end; j += 512) {
        unsigned p = ep[j];
        int r = atomicAdd(&lcur[(p >> 17) & (BSIZE - 1)], 1);
        esrc[r] = (int)(p & 0x1FFFFu);
    }
}

// ---------------- layer 1 ----------------
// 512 thr = 32 nodes x 16 lanes (gather) = 8 waves (MFMA).
// Tile M=32,N=128,K=128. Fragment-major LDS: chunk(tile,kc)=1KB, lane-contig.
// Gather always from bf16 source (x if bf16, else pre-converted xb): 128B/row.
__global__ __launch_bounds__(512, 4) void layer1(
    const void* __restrict__ x, const u16* __restrict__ xb,
    const int* __restrict__ esrc,
    const int* __restrict__ off, const int* __restrict__ cnt,
    const void* __restrict__ W1l, const void* __restrict__ W1r,
    const void* __restrict__ b1, u16* __restrict__ h,
    const int* __restrict__ flags, int nn) {
    __shared__ __align__(16) u16 wB[32 * 512];   // 32 KB, chunks (ntile*4+kc)
    __shared__ __align__(16) u16 wA[8 * 512];    // 8 KB,  chunks (mtile*4+kc)
    __shared__ float b_s[128];
    int tid = threadIdx.x;
    int node0 = blockIdx.x * 32;

    if (flags[1]) {
        const ushort4* s = (const ushort4*)W1l;
        for (int i = tid; i < 2048; i += 512) {
            ushort4 v = s[i]; int k = i >> 5, n = (i & 31) * 4;
            int k8 = k >> 3, kc = k8 >> 2, q = k8 & 3, w = k & 7;
            int base = ((n >> 4) * 4 + kc) * 512 + (q * 16 + (n & 15)) * 8 + w;
            wB[base] = v.x; wB[base + 8] = v.y; wB[base + 16] = v.z; wB[base + 24] = v.w;
        }
    } else {
        const float4* s = (const float4*)W1l;
        for (int i = tid; i < 2048; i += 512) {
            float4 f = s[i]; int k = i >> 5, n = (i & 31) * 4;
            int k8 = k >> 3, kc = k8 >> 2, q = k8 & 3, w = k & 7;
            int base = ((n >> 4) * 4 + kc) * 512 + (q * 16 + (n & 15)) * 8 + w;
            wB[base] = f2bf(f.x); wB[base + 8] = f2bf(f.y);
            wB[base + 16] = f2bf(f.z); wB[base + 24] = f2bf(f.w);
        }
    }
    if (flags[2]) {
        const ushort4* s = (const ushort4*)W1r;
        for (int i = tid; i < 2048; i += 512) {
            ushort4 v = s[i]; int k = i >> 5, n = (i & 31) * 4;
            int k8g = 8 + (k >> 3), kc = k8g >> 2, q = k8g & 3, w = k & 7;
            int base = ((n >> 4) * 4 + kc) * 512 + (q * 16 + (n & 15)) * 8 + w;
            wB[base] = v.x; wB[base + 8] = v.y; wB[base + 16] = v.z; wB[base + 24] = v.w;
        }
    } else {
        const float4* s = (const float4*)W1r;
        for (int i = tid; i < 2048; i += 512) {
            float4 f = s[i]; int k = i >> 5, n = (i & 31) * 4;
            int k8g = 8 + (k >> 3), kc = k8g >> 2, q = k8g & 3, w = k & 7;
            int base = ((n >> 4) * 4 + kc) * 512 + (q * 16 + (n & 15)) * 8 + w;
            wB[base] = f2bf(f.x); wB[base + 8] = f2bf(f.y);
            wB[base + 16] = f2bf(f.z); wB[base + 24] = f2bf(f.w);
        }
    }
    if (tid < 128) b_s[tid] = flags[3] ? bf2f(((const u16*)b1)[tid]) : ((const float*)b1)[tid];

    int grp = tid >> 4, gl = tid & 15;
    int n = node0 + grp;
    int mtile = grp >> 4, l15m = grp & 15;
    int idx_mean = (mtile * 4 + (gl >> 3)) * 512 + (((gl >> 1) & 3) * 16 + l15m) * 8 + (gl & 1) * 4;
    int idx_x = (mtile * 4 + 2 + (gl >> 3)) * 512 + (((gl >> 1) & 3) * 16 + l15m) * 8 + (gl & 1) * 4;
    const u16* xs = flags[0] ? (const u16*)x : xb;
    if (n < nn) {
        int beg = off[n], deg = cnt[n];
        float a0 = 0.f, a1 = 0.f, a2 = 0.f, a3 = 0.f;
        int i = 0;
        const u16* xbp = xs + gl * 4;
        for (; i + 8 <= deg; i += 8) {
            ushort4 v[8];
#pragma unroll
            for (int j = 0; j < 8; j++) {
                int s0 = esrc[beg + i + j];
                v[j] = *(const ushort4*)(xbp + (size_t)s0 * 64);
            }
#pragma unroll
            for (int j = 0; j < 8; j++) {
                a0 += bf2f(v[j].x); a1 += bf2f(v[j].y);
                a2 += bf2f(v[j].z); a3 += bf2f(v[j].w);
            }
        }
        for (; i < deg; i++) {
            int s0 = esrc[beg + i];
            ushort4 v = *(const ushort4*)(xbp + (size_t)s0 * 64);
            a0 += bf2f(v.x); a1 += bf2f(v.y); a2 += bf2f(v.z); a3 += bf2f(v.w);
        }
        float inv = 1.0f / (float)(deg > 0 ? deg : 1);
        *(ushort4*)&wA[idx_mean] =
            make_ushort4(f2bf(a0 * inv), f2bf(a1 * inv), f2bf(a2 * inv), f2bf(a3 * inv));
        *(ushort4*)&wA[idx_x] = *(const ushort4*)(xs + (size_t)n * 64 + gl * 4);
    } else {
        *(ushort4*)&wA[idx_mean] = make_ushort4(0, 0, 0, 0);
        *(ushort4*)&wA[idx_x] = make_ushort4(0, 0, 0, 0);
    }
    __syncthreads();

    int wv = tid >> 6, lane = tid & 63;
    int l15 = lane & 15, q = lane >> 4;
    f32x4 acc0 = {0.f, 0.f, 0.f, 0.f};
    f32x4 acc1 = {0.f, 0.f, 0.f, 0.f};
#pragma unroll
    for (int kc = 0; kc < 4; kc++) {
        short8 a0 = *(const short8*)&wA[(kc) * 512 + lane * 8];
        short8 a1 = *(const short8*)&wA[(4 + kc) * 512 + lane * 8];
        short8 b  = *(const short8*)&wB[(wv * 4 + kc) * 512 + lane * 8];
        acc0 = __builtin_amdgcn_mfma_f32_16x16x32_bf16(a0, b, acc0, 0, 0, 0);
        acc1 = __builtin_amdgcn_mfma_f32_16x16x32_bf16(a1, b, acc1, 0, 0, 0);
    }
    int nc = wv * 16 + l15;
    float bias = b_s[nc];
#pragma unroll
    for (int r = 0; r < 4; r++) {
        int m = q * 4 + r;
        int nd = node0 + m;
        if (nd < nn) h[(size_t)nd * 128 + nc] = f2bf(fmaxf(acc0[r] + bias, 0.0f));
        nd = node0 + 16 + m;
        if (nd < nn) h[(size_t)nd * 128 + nc] = f2bf(fmaxf(acc1[r] + bias, 0.0f));
    }
}

// ---------------- pre2: g = h @ W2_l  (bf16 [N,64]) ----------------
// 256 thr = 4 waves x 16 nodes. Per wave: M=16, N=64, K=128 -> 16 MFMAs.
// A frags read straight from global h (sequential-ish); W2_l staged in LDS.
__global__ __launch_bounds__(256, 8) void pre2(
    const u16* __restrict__ h, const void* __restrict__ W2l,
    u16* __restrict__ g, const int* __restrict__ flags, int nn) {
    __shared__ __align__(16) u16 wB[16 * 512];   // 16 KB, chunks (ntile*4+kc)
    int tid = threadIdx.x;
    int node0 = blockIdx.x * 64;
    if (flags[4]) {
        const ushort4* s = (const ushort4*)W2l;
        for (int i = tid; i < 2048; i += 256) {
            ushort4 v = s[i]; int k = i >> 4, n = (i & 15) * 4;
            int k8 = k >> 3, kc = k8 >> 2, q = k8 & 3, w = k & 7;
            int base = ((n >> 4) * 4 + kc) * 512 + (q * 16 + (n & 15)) * 8 + w;
            wB[base] = v.x; wB[base + 8] = v.y; wB[base + 16] = v.z; wB[base + 24] = v.w;
        }
    } else {
        const float4* s = (const float4*)W2l;
        for (int i = tid; i < 2048; i += 256) {
            float4 f = s[i]; int k = i >> 4, n = (i & 15) * 4;
            int k8 = k >> 3, kc = k8 >> 2, q = k8 & 3, w = k & 7;
            int base = ((n >> 4) * 4 + kc) * 512 + (q * 16 + (n & 15)) * 8 + w;
            wB[base] = f2bf(f.x); wB[base + 8] = f2bf(f.y);
            wB[base + 16] = f2bf(f.z); wB[base + 24] = f2bf(f.w);
        }
    }
    __syncthreads();

    int wv = tid >> 6, lane = tid & 63;
    int l15 = lane & 15, q = lane >> 4;
    int arow = node0 + wv * 16 + l15;
    if (arow >= nn) arow = nn - 1;               // clamp; stores are guarded
    const u16* hrow = h + (size_t)arow * 128 + q * 8;
    f32x4 acc[4];
#pragma unroll
    for (int nt = 0; nt < 4; nt++) acc[nt] = (f32x4){0.f, 0.f, 0.f, 0.f};
#pragma unroll
    for (int kc = 0; kc < 4; kc++) {
        short8 a = *(const short8*)(hrow + kc * 32);
#pragma unroll
        for (int nt = 0; nt < 4; nt++) {
            short8 b = *(const short8*)&wB[(nt * 4 + kc) * 512 + lane * 8];
            acc[nt] = __builtin_amdgcn_mfma_f32_16x16x32_bf16(a, b, acc[nt], 0, 0, 0);
        }
    }
#pragma unroll
    for (int nt = 0; nt < 4; nt++) {
        int nc = nt * 16 + l15;
#pragma unroll
        for (int r = 0; r < 4; r++) {
            int nd = node0 + wv * 16 + q * 4 + r;
            if (nd < nn) g[(size_t)nd * 64 + nc] = f2bf(acc[nt][r]);
        }
    }
}

// ---------------- layer 2 ----------------
// out = mean(g[src]) + h @ W2_r + b2.
// Gather reads 128B g-rows (half of before); self-term MFMA M=32,N=64,K=128.
__global__ __launch_bounds__(512, 8) void layer2(
    const u16* __restrict__ h, const u16* __restrict__ g,
    const int* __restrict__ esrc,
    const int* __restrict__ off, const int* __restrict__ cnt,
    const void* __restrict__ W2r, const void* __restrict__ b2,
    void* __restrict__ out, const int* __restrict__ flags, int nn) {
    __shared__ __align__(16) u16 wBr[16 * 512];      // 16 KB, (ntile*4+kc)
    __shared__ __align__(16) u16 wA2[8 * 512];       // 8 KB,  (mtile*4+kc)
    __shared__ __align__(16) float meanbuf[32][72];  // 9 KB (stride 72: 2-way max)
    __shared__ float b_s[64];
    int tid = threadIdx.x;
    int node0 = blockIdx.x * 32;
    int obf = flags[0];

    if (flags[5]) {
        const ushort4* s = (const ushort4*)W2r;
        for (int i = tid; i < 2048; i += 512) {
            ushort4 v = s[i]; int k = i >> 4, n = (i & 15) * 4;
            int k8 = k >> 3, kc = k8 >> 2, q = k8 & 3, w = k & 7;
            int base = ((n >> 4) * 4 + kc) * 512 + (q * 16 + (n & 15)) * 8 + w;
            wBr[base] = v.x; wBr[base + 8] = v.y; wBr[base + 16] = v.z; wBr[base + 24] = v.w;
        }
    } else {
        const float4* s = (const float4*)W2r;
        for (int i = tid; i < 2048; i += 512) {
            float4 f = s[i]; int k = i >> 4, n = (i & 15) * 4;
            int k8 = k >> 3, kc = k8 >> 2, q = k8 & 3, w = k & 7;
            int base = ((n >> 4) * 4 + kc) * 512 + (q * 16 + (n & 15)) * 8 + w;
            wBr[base] = f2bf(f.x); wBr[base + 8] = f2bf(f.y);
            wBr[base + 16] = f2bf(f.z); wBr[base + 24] = f2bf(f.w);
        }
    }
    if (tid < 64) b_s[tid] = flags[6] ? bf2f(((const u16*)b2)[tid]) : ((const float*)b2)[tid];

    int grp = tid >> 4, gl = tid & 15;
    int n = node0 + grp;
    int mtile = grp >> 4, m15 = grp & 15;
    int idx_h = (mtile * 4 + (gl >> 2)) * 512 + ((gl & 3) * 16 + m15) * 8;
    if (n < nn) {
        // stage self row h[n] into fragment-major LDS
        *(uint4*)&wA2[idx_h] = *(const uint4*)(h + (size_t)n * 128 + gl * 8);
        // gather-mean of g rows (64 bf16 = 128B; this lane covers cols gl*4..+3)
        int beg = off[n], deg = cnt[n];
        float a0 = 0.f, a1 = 0.f, a2 = 0.f, a3 = 0.f;
        const u16* gb = g + gl * 4;
        int i = 0;
        for (; i + 8 <= deg; i += 8) {
            uint2 v[8];
#pragma unroll
            for (int j = 0; j < 8; j++) {
                int s0 = esrc[beg + i + j];
                v[j] = *(const uint2*)(gb + (size_t)s0 * 64);
            }
#pragma unroll
            for (int j = 0; j < 8; j++) {
                a0 += bfu_lo(v[j].x); a1 += bfu_hi(v[j].x);
                a2 += bfu_lo(v[j].y); a3 += bfu_hi(v[j].y);
            }
        }
        for (; i < deg; i++) {
            int s0 = esrc[beg + i];
            uint2 v = *(const uint2*)(gb + (size_t)s0 * 64);
            a0 += bfu_lo(v.x); a1 += bfu_hi(v.x);
            a2 += bfu_lo(v.y); a3 += bfu_hi(v.y);
        }
        float inv = 1.0f / (float)(deg > 0 ? deg : 1);
        *(float4*)&meanbuf[grp][gl * 4] =
            make_float4(a0 * inv, a1 * inv, a2 * inv, a3 * inv);
    } else {
        *(uint4*)&wA2[idx_h] = make_uint4(0, 0, 0, 0);
        *(float4*)&meanbuf[grp][gl * 4] = make_float4(0.f, 0.f, 0.f, 0.f);
    }
    __syncthreads();

    int wv = tid >> 6, lane = tid & 63;
    int l15 = lane & 15, q = lane >> 4;
    int mt = wv >> 2, nt = wv & 3;
    f32x4 acc = {0.f, 0.f, 0.f, 0.f};
#pragma unroll
    for (int kc = 0; kc < 4; kc++) {
        short8 a = *(const short8*)&wA2[(mt * 4 + kc) * 512 + lane * 8];
        short8 b = *(const short8*)&wBr[(nt * 4 + kc) * 512 + lane * 8];
        acc = __builtin_amdgcn_mfma_f32_16x16x32_bf16(a, b, acc, 0, 0, 0);
    }
    int nc = nt * 16 + l15;
    float bias = b_s[nc];
#pragma unroll
    for (int r = 0; r < 4; r++) {
        int m = mt * 16 + q * 4 + r;
        int nd = node0 + m;
        if (nd < nn) {
            float v = acc[r] + bias + meanbuf[m][nc];
            if (obf) ((u16*)out)[(size_t)nd * 64 + nc] = f2bf(v);
            else     ((float*)out)[(size_t)nd * 64 + nc] = v;
        }
    }
}

// ---------------- fallback ----------------
__global__ __launch_bounds__(256) void zero_out_k(u16* __restrict__ out, int n) {
    int i = blockIdx.x * 256 + threadIdx.x;
    if (i < n) out[i] = 0;
}

extern "C" void kernel_launch(void* const* d_in, const int* in_sizes, int n_in,
                              void* d_out, int out_size, void* d_ws, size_t ws_size,
                              hipStream_t stream) {
    const void* x   = d_in[0];
    const void* ei  = d_in[1];
    const void* W1l = d_in[2];
    const void* W1r = d_in[3];
    const void* b1  = d_in[4];
    const void* W2l = d_in[5];
    const void* W2r = d_in[6];
    const void* b2  = d_in[7];

    int nn = in_sizes[0] / 64;
    int ne = in_sizes[1] / 2;
    int nb = (nn + BSIZE - 1) / BSIZE;
    int nchunk = (ne + CHUNK - 1) / CHUNK;

    auto al = [](size_t v) { return (v + 255) & ~(size_t)255; };
    size_t o_flags = 0;
    size_t o_bo    = 256;                              // (nb+1) ints
    size_t o_btot  = al(o_bo + 513 * 4);               // 512 ints
    size_t o_cnt   = al(o_btot + 512 * 4);
    size_t o_off   = al(o_cnt + (size_t)nn * 4);
    size_t o_esrc  = al(o_off + (size_t)nn * 4);
    size_t o_h     = al(o_esrc + (size_t)ne * 4);
    size_t o_g     = al(o_h + (size_t)nn * 128 * 2);   // xb (layer1) then g (layer2)
    size_t ws_req  = o_g + (size_t)nn * 64 * 2;

    // overlays inside the h region (all dead before layer1 writes h):
    size_t o_ep   = o_h;                               // ne*4 B
    size_t o_h2d  = al(o_ep + (size_t)ne * 4);         // nb*NCP*4
    size_t o_b2d  = al(o_h2d + (size_t)512 * NCP * 4); // nb*NCP*4
    size_t ov_end = o_b2d + (size_t)512 * NCP * 4;

    bool ok = ws_size >= ws_req && nb >= 1 && nb <= 512 && nn <= 131072 &&
              nchunk <= NCP && ov_end <= o_g;
    if (!ok) {
        zero_out_k<<<(out_size + 255) / 256, 256, 0, stream>>>((u16*)d_out, out_size);
        return;
    }

    char* ws = (char*)d_ws;
    int* flags  = (int*)(ws + o_flags);
    int* bo     = (int*)(ws + o_bo);
    int* btot   = (int*)(ws + o_btot);
    int* cnt    = (int*)(ws + o_cnt);
    int* off    = (int*)(ws + o_off);
    int* esrc   = (int*)(ws + o_esrc);
    u16* h      = (u16*)(ws + o_h);
    u16* xbg    = (u16*)(ws + o_g);                    // xb, later g
    unsigned* ep = (unsigned*)(ws + o_ep);
    int* hist2d = (int*)(ws + o_h2d);
    int* base2d = (int*)(ws + o_b2d);

    probe_k<<<1, 256, 0, stream>>>(x, W1l, W1r, b1, W2l, W2r, b2, ei, flags, ne,
                                   in_sizes[0], in_sizes[2], in_sizes[3], in_sizes[4],
                                   in_sizes[5], in_sizes[6], in_sizes[7]);
    int n4 = nn * 16;   // nn*64/4 float4 groups
    convert_x<<<(n4 + 255) / 256, 256, 0, stream>>>(x, xbg, flags, n4);
    count_chunks<<<nchunk, 512, 0, stream>>>(ei, hist2d, flags, nn, ne, nb);
    scan2d<<<nb, 256, 0, stream>>>(hist2d, base2d, btot, nchunk);
    scan_buckets<<<1, 512, 0, stream>>>(btot, bo, nb);
    partition_k<<<nchunk, 512, 0, stream>>>(ei, bo, base2d, ep, flags, nn, ne, nb);
    csr_fill2<<<nb, 512, 0, stream>>>(ep, bo, off, cnt, esrc, nn);
    int lb = (nn + 31) / 32;
    layer1<<<lb, 512, 0, stream>>>(x, xbg, esrc, off, cnt, W1l, W1r, b1, h, flags, nn);
    pre2<<<(nn + 63) / 64, 256, 0, stream>>>(h, W2l, xbg, flags, nn);
    layer2<<<lb, 512, 0, stream>>>(h, xbg, esrc, off, cnt, W2r, b2, d_out, flags, nn);
}

// Round 2
// 245.573 us; speedup vs baseline: 1.2149x; 1.0760x over previous
//
#include <hip/hip_runtime.h>
#include <hip/hip_bf16.h>
#include <stdint.h>

// GraphSAGE 2-layer encoder — atomic-free bucketed CSR build + MFMA layers.
// R13: weights packed ONCE into fragment-major layout in global ws (prep_w);
// layer1/pre2/layer2 read B fragments directly from global (L2-resident,
// 64KB total). Kills the per-block LDS weight staging (25M bank conflicts,
// 32KB LDS, staging VALU) -> layer1 LDS 41.5->8.7KB, launch_bounds(512,8).
// R12 retained: pre2 g = h @ W2_l (linearity of mean), 128B gather rows,
// x pre-converted to bf16 (convert_x).

typedef unsigned short u16;
typedef __attribute__((ext_vector_type(8))) short short8;   // bf16x8 A/B frag
typedef __attribute__((ext_vector_type(4))) float f32x4;    // fp32x4 C/D frag

#define BSHIFT 9
#define BSIZE  512          // nodes per bucket
#define CHUNK  8192         // edges per partition block
#define NCP    256          // padded chunks-per-bucket stride (nchunk <= 256)

__device__ __forceinline__ float bf2f(u16 v) { return __uint_as_float(((uint32_t)v) << 16); }
__device__ __forceinline__ float bfu_lo(uint32_t u) { return __uint_as_float(u << 16); }
__device__ __forceinline__ float bfu_hi(uint32_t u) { return __uint_as_float(u & 0xffff0000u); }
__device__ __forceinline__ u16 f2bf(float f) {
    uint32_t u = __float_as_uint(f);
    return (u16)((u + 0x7fffu + ((u >> 16) & 1u)) >> 16);
}

// ---------------- probe: dtype flags ----------------
__global__ __launch_bounds__(256) void probe_k(
    const void* x, const void* w1l, const void* w1r, const void* b1,
    const void* w2l, const void* w2r, const void* b2, const void* ei,
    int* __restrict__ flags, int ne,
    int c0, int c1, int c2, int c3, int c4, int c5, int c6) {
    __shared__ int cs_s[8];
    int tid = threadIdx.x, a = tid >> 5, lane = tid & 31;
    if (tid < 8) cs_s[tid] = 0;
    __syncthreads();
    if (a < 7) {
        const void* ptrs[7] = {x, w1l, w1r, b1, w2l, w2r, b2};
        int cs[7] = {c0, c1, c2, c3, c4, c5, c6};
        int C = cs[a];
        int stride = C / 32; if (stride < 1) stride = 1;
        long long i = (long long)lane * stride;
        if (i > C - 1) i = C - 1;
        i &= ~1LL;
        u16 v = ((const u16*)ptrs[a])[i];
        int e = (v >> 7) & 0xFF;
        int sane = ((e >= 0x50 && e <= 0x97) || v == 0) ? 1 : 0;
        atomicAdd(&cs_s[a], sane);
    } else {
        long long n32 = 2LL * ne;
        long long stride = n32 / 32; if (stride < 1) stride = 1;
        long long i = (long long)lane * stride; i |= 1;
        if (i >= n32) i = 1;
        int wv = ((const int*)ei)[i];
        atomicAdd(&cs_s[7], wv != 0 ? 1 : 0);
    }
    __syncthreads();
    if (tid < 7) flags[tid] = (cs_s[tid] >= 24) ? 1 : 0;
    if (tid == 7) flags[7] = (cs_s[7] == 0) ? 1 : 0;
}

// ---------------- pack weights into fragment-major layout (once) ----------
// wpk u16 layout:
//   [0,     16384) layer1 B: 32 chunks x 512 (W1l -> kc 0..1, W1r -> kc 2..3)
//   [16384, 24576) pre2  B: 16 chunks x 512 (W2l, K=128, N=64)
//   [24576, 32768) layer2 B: 16 chunks x 512 (W2r, K=128, N=64)
__global__ __launch_bounds__(512) void prep_w(
    const void* __restrict__ W1l, const void* __restrict__ W1r,
    const void* __restrict__ W2l, const void* __restrict__ W2r,
    u16* __restrict__ wpk, const int* __restrict__ flags) {
    int tid = threadIdx.x;
    int b = blockIdx.x;
    const void* src = (b == 0) ? W1l : (b == 1) ? W1r : (b == 2) ? W2l : W2r;
    int isbf = flags[(b == 0) ? 1 : (b == 1) ? 2 : (b == 2) ? 4 : 5];
    u16* dst = wpk + ((b >= 2) ? (16384 + (b - 2) * 8192) : 0);
    for (int i = tid; i < 2048; i += 512) {
        u16 v0, v1, v2, v3;
        if (isbf) {
            ushort4 u = ((const ushort4*)src)[i];
            v0 = u.x; v1 = u.y; v2 = u.z; v3 = u.w;
        } else {
            float4 u = ((const float4*)src)[i];
            v0 = f2bf(u.x); v1 = f2bf(u.y); v2 = f2bf(u.z); v3 = f2bf(u.w);
        }
        int k, n, k8;
        if (b <= 1) { k = i >> 5; n = (i & 31) * 4; k8 = (b == 1 ? 8 : 0) + (k >> 3); }
        else        { k = i >> 4; n = (i & 15) * 4; k8 = k >> 3; }
        int kc = k8 >> 2, q = k8 & 3, w = k & 7;
        int base = ((n >> 4) * 4 + kc) * 512 + (q * 16 + (n & 15)) * 8 + w;
        dst[base] = v0; dst[base + 8] = v1; dst[base + 16] = v2; dst[base + 24] = v3;
    }
}

// ---------------- x -> bf16 (only if x is f32) ----------------
__global__ __launch_bounds__(256) void convert_x(
    const void* __restrict__ x, u16* __restrict__ xb,
    const int* __restrict__ flags, int n4) {
    if (flags[0]) return;   // x already bf16 — layer1 reads it directly
    int i = blockIdx.x * 256 + threadIdx.x;
    if (i < n4) {
        float4 f = ((const float4*)x)[i];
        *(ushort4*)&xb[(size_t)i * 4] =
            make_ushort4(f2bf(f.x), f2bf(f.y), f2bf(f.z), f2bf(f.w));
    }
}

// ---------------- per-chunk bucket histogram (no global atomics) ----------
__global__ __launch_bounds__(512) void count_chunks(
    const void* __restrict__ ei, int* __restrict__ hist2d,
    const int* __restrict__ flags, int nn, int ne, int nb) {
    __shared__ int hist[512];
    int tid = threadIdx.x;
    hist[tid] = 0;
    __syncthreads();
    int e64 = flags[7];
    int base = blockIdx.x * CHUNK;
#pragma unroll
    for (int j = 0; j < 16; j++) {
        int e = base + j * 512 + tid;
        if (e < ne) {
            int dst = e64 ? (int)((const long long*)ei)[(size_t)ne + e]
                          : ((const int*)ei)[(size_t)ne + e];
            if ((unsigned)dst < (unsigned)nn) atomicAdd(&hist[dst >> BSHIFT], 1);
        }
    }
    __syncthreads();
    for (int b = tid; b < nb; b += 512)
        hist2d[b * NCP + blockIdx.x] = hist[b];
}

// ---------------- per-bucket scan over chunks ----------------
__global__ __launch_bounds__(256) void scan2d(
    const int* __restrict__ hist2d, int* __restrict__ base2d,
    int* __restrict__ btot, int nchunk) {
    __shared__ int t0[256];
    int b = blockIdx.x, tid = threadIdx.x;
    int v = (tid < nchunk) ? hist2d[b * NCP + tid] : 0;
    t0[tid] = v;
    __syncthreads();
    for (int d = 1; d < 256; d <<= 1) {
        int t = (tid >= d) ? t0[tid - d] : 0;
        __syncthreads();
        t0[tid] += t;
        __syncthreads();
    }
    if (tid < nchunk) base2d[b * NCP + tid] = t0[tid] - v;
    if (tid == 255) btot[b] = t0[255];
}

// ---------------- bucket scan ----------------
__global__ __launch_bounds__(512) void scan_buckets(
    const int* __restrict__ btot, int* __restrict__ bo, int nb) {
    __shared__ int t0[512];
    int tid = threadIdx.x;
    int v = (tid < nb) ? btot[tid] : 0;
    t0[tid] = v;
    __syncthreads();
    for (int d = 1; d < 512; d <<= 1) {
        int t = (tid >= d) ? t0[tid - d] : 0;
        __syncthreads();
        t0[tid] += t;
        __syncthreads();
    }
    if (tid < nb) bo[tid] = t0[tid] - v;
    if (tid == 511) bo[nb] = t0[511];
}

// ---------------- partition: bucket-grouped packed edges, atomic-free -----
__global__ __launch_bounds__(512) void partition_k(
    const void* __restrict__ ei, const int* __restrict__ bo,
    const int* __restrict__ base2d,
    unsigned* __restrict__ ep, const int* __restrict__ flags,
    int nn, int ne, int nb) {
    __shared__ unsigned stage[CHUNK];    // 32 KB
    __shared__ u16 ab[CHUNK];            // 16 KB
    __shared__ int hist[512], incl[512], exl[512], gbase[512], lcur[512];
    int tid = threadIdx.x;
    int base = blockIdx.x * CHUNK;
    hist[tid] = 0;
    __syncthreads();
    int e64 = flags[7];
    unsigned pk[16]; int bk[16];
#pragma unroll
    for (int j = 0; j < 16; j++) {
        int e = base + j * 512 + tid;
        bk[j] = -1;
        pk[j] = 0;
        if (e < ne) {
            int src, dst;
            if (e64) {
                src = (int)((const long long*)ei)[e];
                dst = (int)((const long long*)ei)[(size_t)ne + e];
            } else {
                src = ((const int*)ei)[e];
                dst = ((const int*)ei)[(size_t)ne + e];
            }
            if ((unsigned)dst < (unsigned)nn) {
                if ((unsigned)src >= (unsigned)nn) src = 0;
                bk[j] = dst >> BSHIFT;
                pk[j] = (unsigned)src | ((unsigned)(dst & (BSIZE - 1)) << 17);
                atomicAdd(&hist[bk[j]], 1);
            }
        }
    }
    __syncthreads();
    incl[tid] = hist[tid];
    __syncthreads();
    for (int d = 1; d < 512; d <<= 1) {
        int t = (tid >= d) ? incl[tid - d] : 0;
        __syncthreads();
        incl[tid] += t;
        __syncthreads();
    }
    int ex = incl[tid] - hist[tid];
    exl[tid] = ex;
    lcur[tid] = ex;
    gbase[tid] = (tid < nb) ? (bo[tid] + base2d[tid * NCP + blockIdx.x]) : 0;
    __syncthreads();
#pragma unroll
    for (int j = 0; j < 16; j++) {
        if (bk[j] >= 0) {
            int r = atomicAdd(&lcur[bk[j]], 1);
            stage[r] = pk[j];
            ab[r] = (u16)bk[j];
        }
    }
    __syncthreads();
    int tot = incl[511];
    for (int j = tid; j < tot; j += 512) {
        int b = ab[j];
        ep[gbase[b] + (j - exl[b])] = stage[j];
    }
}

// ---------------- per-bucket CSR finalize ----------------
__global__ __launch_bounds__(512) void csr_fill2(
    const unsigned* __restrict__ ep, const int* __restrict__ bo,
    int* __restrict__ off, int* __restrict__ cnt, int* __restrict__ esrc,
    int nn) {
    __shared__ int hist[BSIZE], incl[BSIZE], lcur[BSIZE];
    int b = blockIdx.x;
    int beg = bo[b], end = bo[b + 1];
    int tid = threadIdx.x;
    hist[tid] = 0;
    __syncthreads();
    for (int j = beg + tid; j < end; j += 512)
        atomicAdd(&hist[(ep[j] >> 17) & (BSIZE - 1)], 1);
    __syncthreads();
    incl[tid] = hist[tid];
    __syncthreads();
    for (int d = 1; d < 512; d <<= 1) {
        int t = (tid >= d) ? incl[tid - d] : 0;
        __syncthreads();
        incl[tid] += t;
        __syncthreads();
    }
    int ex = beg + incl[tid] - hist[tid];
    lcur[tid] = ex;
    int node = b * BSIZE + tid;
    if (node < nn) { off[node] = ex; cnt[node] = hist[tid]; }
    __syncthreads();
    for (int j = beg + tid; j < end; j += 512) {
        unsigned p = ep[j];
        int r = atomicAdd(&lcur[(p >> 17) & (BSIZE - 1)], 1);
        esrc[r] = (int)(p & 0x1FFFFu);
    }
}

// ---------------- layer 1 ----------------
// 512 thr = 32 nodes x 16 lanes (gather) = 8 waves (MFMA).
// Tile M=32,N=128,K=128. A (gather result) in fragment-major LDS (8KB);
// B read directly from packed global wpk (L2-resident, 32KB).
__global__ __launch_bounds__(512, 8) void layer1(
    const void* __restrict__ x, const u16* __restrict__ xb,
    const int* __restrict__ esrc,
    const int* __restrict__ off, const int* __restrict__ cnt,
    const u16* __restrict__ w1g, const void* __restrict__ b1,
    u16* __restrict__ h, const int* __restrict__ flags, int nn) {
    __shared__ __align__(16) u16 wA[8 * 512];    // 8 KB,  chunks (mtile*4+kc)
    __shared__ float b_s[128];
    int tid = threadIdx.x;
    int node0 = blockIdx.x * 32;

    if (tid < 128) b_s[tid] = flags[3] ? bf2f(((const u16*)b1)[tid]) : ((const float*)b1)[tid];

    int grp = tid >> 4, gl = tid & 15;
    int n = node0 + grp;
    int mtile = grp >> 4, l15m = grp & 15;
    int idx_mean = (mtile * 4 + (gl >> 3)) * 512 + (((gl >> 1) & 3) * 16 + l15m) * 8 + (gl & 1) * 4;
    int idx_x = (mtile * 4 + 2 + (gl >> 3)) * 512 + (((gl >> 1) & 3) * 16 + l15m) * 8 + (gl & 1) * 4;
    const u16* xs = flags[0] ? (const u16*)x : xb;
    if (n < nn) {
        int beg = off[n], deg = cnt[n];
        float a0 = 0.f, a1 = 0.f, a2 = 0.f, a3 = 0.f;
        int i = 0;
        const u16* xbp = xs + gl * 4;
        for (; i + 8 <= deg; i += 8) {
            ushort4 v[8];
#pragma unroll
            for (int j = 0; j < 8; j++) {
                int s0 = esrc[beg + i + j];
                v[j] = *(const ushort4*)(xbp + (size_t)s0 * 64);
            }
#pragma unroll
            for (int j = 0; j < 8; j++) {
                a0 += bf2f(v[j].x); a1 += bf2f(v[j].y);
                a2 += bf2f(v[j].z); a3 += bf2f(v[j].w);
            }
        }
        for (; i < deg; i++) {
            int s0 = esrc[beg + i];
            ushort4 v = *(const ushort4*)(xbp + (size_t)s0 * 64);
            a0 += bf2f(v.x); a1 += bf2f(v.y); a2 += bf2f(v.z); a3 += bf2f(v.w);
        }
        float inv = 1.0f / (float)(deg > 0 ? deg : 1);
        *(ushort4*)&wA[idx_mean] =
            make_ushort4(f2bf(a0 * inv), f2bf(a1 * inv), f2bf(a2 * inv), f2bf(a3 * inv));
        *(ushort4*)&wA[idx_x] = *(const ushort4*)(xs + (size_t)n * 64 + gl * 4);
    } else {
        *(ushort4*)&wA[idx_mean] = make_ushort4(0, 0, 0, 0);
        *(ushort4*)&wA[idx_x] = make_ushort4(0, 0, 0, 0);
    }
    __syncthreads();

    int wv = tid >> 6, lane = tid & 63;
    int l15 = lane & 15, q = lane >> 4;
    f32x4 acc0 = {0.f, 0.f, 0.f, 0.f};
    f32x4 acc1 = {0.f, 0.f, 0.f, 0.f};
#pragma unroll
    for (int kc = 0; kc < 4; kc++) {
        short8 a0 = *(const short8*)&wA[(kc) * 512 + lane * 8];
        short8 a1 = *(const short8*)&wA[(4 + kc) * 512 + lane * 8];
        short8 b  = *(const short8*)&w1g[(wv * 4 + kc) * 512 + lane * 8];
        acc0 = __builtin_amdgcn_mfma_f32_16x16x32_bf16(a0, b, acc0, 0, 0, 0);
        acc1 = __builtin_amdgcn_mfma_f32_16x16x32_bf16(a1, b, acc1, 0, 0, 0);
    }
    int nc = wv * 16 + l15;
    float bias = b_s[nc];
#pragma unroll
    for (int r = 0; r < 4; r++) {
        int m = q * 4 + r;
        int nd = node0 + m;
        if (nd < nn) h[(size_t)nd * 128 + nc] = f2bf(fmaxf(acc0[r] + bias, 0.0f));
        nd = node0 + 16 + m;
        if (nd < nn) h[(size_t)nd * 128 + nc] = f2bf(fmaxf(acc1[r] + bias, 0.0f));
    }
}

// ---------------- pre2: g = h @ W2_l  (bf16 [N,64]) ----------------
// 256 thr = 4 waves x 16 nodes. Per wave: M=16, N=64, K=128 -> 16 MFMAs.
// A frags read straight from global h; B from packed global (no LDS at all).
__global__ __launch_bounds__(256, 8) void pre2(
    const u16* __restrict__ h, const u16* __restrict__ w2lg,
    u16* __restrict__ g, int nn) {
    int tid = threadIdx.x;
    int node0 = blockIdx.x * 64;
    int wv = tid >> 6, lane = tid & 63;
    int l15 = lane & 15, q = lane >> 4;
    int arow = node0 + wv * 16 + l15;
    if (arow >= nn) arow = nn - 1;               // clamp; stores are guarded
    const u16* hrow = h + (size_t)arow * 128 + q * 8;
    f32x4 acc[4];
#pragma unroll
    for (int nt = 0; nt < 4; nt++) acc[nt] = (f32x4){0.f, 0.f, 0.f, 0.f};
#pragma unroll
    for (int kc = 0; kc < 4; kc++) {
        short8 a = *(const short8*)(hrow + kc * 32);
#pragma unroll
        for (int nt = 0; nt < 4; nt++) {
            short8 b = *(const short8*)&w2lg[(nt * 4 + kc) * 512 + lane * 8];
            acc[nt] = __builtin_amdgcn_mfma_f32_16x16x32_bf16(a, b, acc[nt], 0, 0, 0);
        }
    }
#pragma unroll
    for (int nt = 0; nt < 4; nt++) {
        int nc = nt * 16 + l15;
#pragma unroll
        for (int r = 0; r < 4; r++) {
            int nd = node0 + wv * 16 + q * 4 + r;
            if (nd < nn) g[(size_t)nd * 64 + nc] = f2bf(acc[nt][r]);
        }
    }
}

// ---------------- layer 2 ----------------
// out = mean(g[src]) + h @ W2_r + b2.
// Gather reads 128B g-rows; self-term MFMA M=32,N=64,K=128; B from global.
__global__ __launch_bounds__(512, 8) void layer2(
    const u16* __restrict__ h, const u16* __restrict__ g,
    const int* __restrict__ esrc,
    const int* __restrict__ off, const int* __restrict__ cnt,
    const u16* __restrict__ w2rg, const void* __restrict__ b2,
    void* __restrict__ out, const int* __restrict__ flags, int nn) {
    __shared__ __align__(16) u16 wA2[8 * 512];       // 8 KB,  (mtile*4+kc)
    __shared__ __align__(16) float meanbuf[32][72];  // 9 KB (stride 72)
    __shared__ float b_s[64];
    int tid = threadIdx.x;
    int node0 = blockIdx.x * 32;
    int obf = flags[0];

    if (tid < 64) b_s[tid] = flags[6] ? bf2f(((const u16*)b2)[tid]) : ((const float*)b2)[tid];

    int grp = tid >> 4, gl = tid & 15;
    int n = node0 + grp;
    int mtile = grp >> 4, m15 = grp & 15;
    int idx_h = (mtile * 4 + (gl >> 2)) * 512 + ((gl & 3) * 16 + m15) * 8;
    if (n < nn) {
        // stage self row h[n] into fragment-major LDS
        *(uint4*)&wA2[idx_h] = *(const uint4*)(h + (size_t)n * 128 + gl * 8);
        // gather-mean of g rows (64 bf16 = 128B; this lane covers cols gl*4..+3)
        int beg = off[n], deg = cnt[n];
        float a0 = 0.f, a1 = 0.f, a2 = 0.f, a3 = 0.f;
        const u16* gb = g + gl * 4;
        int i = 0;
        for (; i + 8 <= deg; i += 8) {
            uint2 v[8];
#pragma unroll
            for (int j = 0; j < 8; j++) {
                int s0 = esrc[beg + i + j];
                v[j] = *(const uint2*)(gb + (size_t)s0 * 64);
            }
#pragma unroll
            for (int j = 0; j < 8; j++) {
                a0 += bfu_lo(v[j].x); a1 += bfu_hi(v[j].x);
                a2 += bfu_lo(v[j].y); a3 += bfu_hi(v[j].y);
            }
        }
        for (; i < deg; i++) {
            int s0 = esrc[beg + i];
            uint2 v = *(const uint2*)(gb + (size_t)s0 * 64);
            a0 += bfu_lo(v.x); a1 += bfu_hi(v.x);
            a2 += bfu_lo(v.y); a3 += bfu_hi(v.y);
        }
        float inv = 1.0f / (float)(deg > 0 ? deg : 1);
        *(float4*)&meanbuf[grp][gl * 4] =
            make_float4(a0 * inv, a1 * inv, a2 * inv, a3 * inv);
    } else {
        *(uint4*)&wA2[idx_h] = make_uint4(0, 0, 0, 0);
        *(float4*)&meanbuf[grp][gl * 4] = make_float4(0.f, 0.f, 0.f, 0.f);
    }
    __syncthreads();

    int wv = tid >> 6, lane = tid & 63;
    int l15 = lane & 15, q = lane >> 4;
    int mt = wv >> 2, nt = wv & 3;
    f32x4 acc = {0.f, 0.f, 0.f, 0.f};
#pragma unroll
    for (int kc = 0; kc < 4; kc++) {
        short8 a = *(const short8*)&wA2[(mt * 4 + kc) * 512 + lane * 8];
        short8 b = *(const short8*)&w2rg[(nt * 4 + kc) * 512 + lane * 8];
        acc = __builtin_amdgcn_mfma_f32_16x16x32_bf16(a, b, acc, 0, 0, 0);
    }
    int nc = nt * 16 + l15;
    float bias = b_s[nc];
#pragma unroll
    for (int r = 0; r < 4; r++) {
        int m = mt * 16 + q * 4 + r;
        int nd = node0 + m;
        if (nd < nn) {
            float v = acc[r] + bias + meanbuf[m][nc];
            if (obf) ((u16*)out)[(size_t)nd * 64 + nc] = f2bf(v);
            else     ((float*)out)[(size_t)nd * 64 + nc] = v;
        }
    }
}

// ---------------- fallback ----------------
__global__ __launch_bounds__(256) void zero_out_k(u16* __restrict__ out, int n) {
    int i = blockIdx.x * 256 + threadIdx.x;
    if (i < n) out[i] = 0;
}

extern "C" void kernel_launch(void* const* d_in, const int* in_sizes, int n_in,
                              void* d_out, int out_size, void* d_ws, size_t ws_size,
                              hipStream_t stream) {
    const void* x   = d_in[0];
    const void* ei  = d_in[1];
    const void* W1l = d_in[2];
    const void* W1r = d_in[3];
    const void* b1  = d_in[4];
    const void* W2l = d_in[5];
    const void* W2r = d_in[6];
    const void* b2  = d_in[7];

    int nn = in_sizes[0] / 64;
    int ne = in_sizes[1] / 2;
    int nb = (nn + BSIZE - 1) / BSIZE;
    int nchunk = (ne + CHUNK - 1) / CHUNK;

    auto al = [](size_t v) { return (v + 255) & ~(size_t)255; };
    size_t o_flags = 0;
    size_t o_bo    = 256;                              // (nb+1) ints
    size_t o_btot  = al(o_bo + 513 * 4);               // 512 ints
    size_t o_wpk   = al(o_btot + 512 * 4);             // 64 KB packed weights
    size_t o_cnt   = al(o_wpk + 65536);
    size_t o_off   = al(o_cnt + (size_t)nn * 4);
    size_t o_esrc  = al(o_off + (size_t)nn * 4);
    size_t o_h     = al(o_esrc + (size_t)ne * 4);
    size_t o_g     = al(o_h + (size_t)nn * 128 * 2);   // xb (layer1) then g (layer2)
    size_t ws_req  = o_g + (size_t)nn * 64 * 2;

    // overlays inside the h region (all dead before layer1 writes h):
    size_t o_ep   = o_h;                               // ne*4 B
    size_t o_h2d  = al(o_ep + (size_t)ne * 4);         // nb*NCP*4
    size_t o_b2d  = al(o_h2d + (size_t)512 * NCP * 4); // nb*NCP*4
    size_t ov_end = o_b2d + (size_t)512 * NCP * 4;

    bool ok = ws_size >= ws_req && nb >= 1 && nb <= 512 && nn <= 131072 &&
              nchunk <= NCP && ov_end <= o_g;
    if (!ok) {
        zero_out_k<<<(out_size + 255) / 256, 256, 0, stream>>>((u16*)d_out, out_size);
        return;
    }

    char* ws = (char*)d_ws;
    int* flags  = (int*)(ws + o_flags);
    int* bo     = (int*)(ws + o_bo);
    int* btot   = (int*)(ws + o_btot);
    u16* wpk    = (u16*)(ws + o_wpk);
    int* cnt    = (int*)(ws + o_cnt);
    int* off    = (int*)(ws + o_off);
    int* esrc   = (int*)(ws + o_esrc);
    u16* h      = (u16*)(ws + o_h);
    u16* xbg    = (u16*)(ws + o_g);                    // xb, later g
    unsigned* ep = (unsigned*)(ws + o_ep);
    int* hist2d = (int*)(ws + o_h2d);
    int* base2d = (int*)(ws + o_b2d);

    probe_k<<<1, 256, 0, stream>>>(x, W1l, W1r, b1, W2l, W2r, b2, ei, flags, ne,
                                   in_sizes[0], in_sizes[2], in_sizes[3], in_sizes[4],
                                   in_sizes[5], in_sizes[6], in_sizes[7]);
    prep_w<<<4, 512, 0, stream>>>(W1l, W1r, W2l, W2r, wpk, flags);
    int n4 = nn * 16;   // nn*64/4 float4 groups
    convert_x<<<(n4 + 255) / 256, 256, 0, stream>>>(x, xbg, flags, n4);
    count_chunks<<<nchunk, 512, 0, stream>>>(ei, hist2d, flags, nn, ne, nb);
    scan2d<<<nb, 256, 0, stream>>>(hist2d, base2d, btot, nchunk);
    scan_buckets<<<1, 512, 0, stream>>>(btot, bo, nb);
    partition_k<<<nchunk, 512, 0, stream>>>(ei, bo, base2d, ep, flags, nn, ne, nb);
    csr_fill2<<<nb, 512, 0, stream>>>(ep, bo, off, cnt, esrc, nn);
    int lb = (nn + 31) / 32;
    layer1<<<lb, 512, 0, stream>>>(x, xbg, esrc, off, cnt, wpk, b1, h, flags, nn);
    pre2<<<(nn + 63) / 64, 256, 0, stream>>>(h, wpk + 16384, xbg, nn);
    layer2<<<lb, 512, 0, stream>>>(h, xbg, esrc, off, cnt, wpk + 24576, b2, d_out, flags, nn);
}

// Round 3
// 228.099 us; speedup vs baseline: 1.3080x; 1.0766x over previous
//
#include <hip/hip_runtime.h>
#include <hip/hip_bf16.h>
#include <stdint.h>

// GraphSAGE 2-layer encoder — atomic-free bucketed CSR build + MFMA layers.
// R14: launch-graph compression (10 -> 6 kernels):
//   setup_k  = probe + convert_x + count_chunks + prep_w (block roles,
//              per-role inline dtype detection via 32-lane sample + ballot)
//   scan_buckets deleted: partition_k / csr_fill2 inline the bucket scan
//   pre2 fused into layer1 (h-tile staged fragment-major in wA, +4 MFMA/wave,
//              g stored directly) when ws_size permits a dedicated g region;
//              else auto-fallback to separate pre2.
//   gather batch 8 -> 16 in layer1/layer2.
// R13 retained: weights packed once (fragment-major, global, L2-resident).
// R12 retained: g = h @ W2_l linearity, 128B gather rows, x -> bf16 once.

typedef unsigned short u16;
typedef __attribute__((ext_vector_type(8))) short short8;   // bf16x8 A/B frag
typedef __attribute__((ext_vector_type(4))) float f32x4;    // fp32x4 C/D frag

#define BSHIFT 9
#define BSIZE  512          // nodes per bucket
#define CHUNK  8192         // edges per partition block
#define NCP    256          // padded chunks-per-bucket stride (nchunk <= 256)

__device__ __forceinline__ float bf2f(u16 v) { return __uint_as_float(((uint32_t)v) << 16); }
__device__ __forceinline__ float bfu_lo(uint32_t u) { return __uint_as_float(u << 16); }
__device__ __forceinline__ float bfu_hi(uint32_t u) { return __uint_as_float(u & 0xffff0000u); }
__device__ __forceinline__ u16 f2bf(float f) {
    uint32_t u = __float_as_uint(f);
    return (u16)((u + 0x7fffu + ((u >> 16) & 1u)) >> 16);
}

// ---------------- setup: probe + convert_x + count_chunks + prep_w --------
// grid = nchunk (count) + ncvt (convert) + 4 (prep) + 1 (probe flags)
__global__ __launch_bounds__(512) void setup_k(
    const void* __restrict__ x, const void* __restrict__ ei,
    const void* __restrict__ W1l, const void* __restrict__ W1r,
    const void* __restrict__ b1, const void* __restrict__ W2l,
    const void* __restrict__ W2r, const void* __restrict__ b2,
    u16* __restrict__ wpk, u16* __restrict__ xb,
    int* __restrict__ hist2d, int* __restrict__ flags,
    int nn, int ne, int nb, int nchunk, int ncvt,
    int c0, int c1, int c2, int c3, int c4, int c5, int c6) {
    __shared__ int sh[512];
    __shared__ int sflag;
    int bid = blockIdx.x, tid = threadIdx.x;
    if (bid < nchunk) {
        // ---- count role (inline e64 detect) ----
        sh[tid] = 0;
        int samp = 0;
        if (tid < 32) {
            long long n32 = 2LL * ne;
            long long stride = n32 / 32; if (stride < 1) stride = 1;
            long long i = (long long)tid * stride; i |= 1;
            if (i >= n32) i = 1;
            samp = (((const int*)ei)[i] != 0);
        }
        unsigned long long m = __ballot(samp);
        if (tid == 0) sflag = (m == 0ULL) ? 1 : 0;
        __syncthreads();
        int e64 = sflag;
        int base = bid * CHUNK;
#pragma unroll
        for (int j = 0; j < 16; j++) {
            int e = base + j * 512 + tid;
            if (e < ne) {
                int dst = e64 ? (int)((const long long*)ei)[(size_t)ne + e]
                              : ((const int*)ei)[(size_t)ne + e];
                if ((unsigned)dst < (unsigned)nn) atomicAdd(&sh[dst >> BSHIFT], 1);
            }
        }
        __syncthreads();
        for (int b = tid; b < nb; b += 512)
            hist2d[b * NCP + bid] = sh[b];
    } else if (bid < nchunk + ncvt) {
        // ---- convert role (inline x-dtype detect) ----
        int samp = 0;
        if (tid < 32) {
            int C = c0; int stride = C / 32; if (stride < 1) stride = 1;
            long long i = (long long)tid * stride;
            if (i > C - 1) i = C - 1; i &= ~1LL;
            u16 v = ((const u16*)x)[i];
            int e = (v >> 7) & 0xFF;
            samp = ((e >= 0x50 && e <= 0x97) || v == 0) ? 1 : 0;
        }
        unsigned long long m = __ballot(samp);
        if (tid == 0) sflag = (__popcll(m) >= 24) ? 1 : 0;
        __syncthreads();
        if (sflag) return;   // x already bf16 — layer1 reads it directly
        int i = (bid - nchunk) * 512 + tid;
        if (i < nn * 16) {
            float4 f = ((const float4*)x)[i];
            *(ushort4*)&xb[(size_t)i * 4] =
                make_ushort4(f2bf(f.x), f2bf(f.y), f2bf(f.z), f2bf(f.w));
        }
    } else if (bid < nchunk + ncvt + 4) {
        // ---- prep role: pack one weight matrix, fragment-major ----
        int b = bid - nchunk - ncvt;
        const void* src = (b == 0) ? W1l : (b == 1) ? W1r : (b == 2) ? W2l : W2r;
        int C = (b == 0) ? c1 : (b == 1) ? c2 : (b == 2) ? c4 : c5;
        int samp = 0;
        if (tid < 32) {
            int stride = C / 32; if (stride < 1) stride = 1;
            long long i = (long long)tid * stride;
            if (i > C - 1) i = C - 1; i &= ~1LL;
            u16 v = ((const u16*)src)[i];
            int e = (v >> 7) & 0xFF;
            samp = ((e >= 0x50 && e <= 0x97) || v == 0) ? 1 : 0;
        }
        unsigned long long m = __ballot(samp);
        if (tid == 0) sflag = (__popcll(m) >= 24) ? 1 : 0;
        __syncthreads();
        int isbf = sflag;
        u16* dst = wpk + ((b >= 2) ? (16384 + (b - 2) * 8192) : 0);
        for (int i = tid; i < 2048; i += 512) {
            u16 v0, v1, v2, v3;
            if (isbf) {
                ushort4 u = ((const ushort4*)src)[i];
                v0 = u.x; v1 = u.y; v2 = u.z; v3 = u.w;
            } else {
                float4 u = ((const float4*)src)[i];
                v0 = f2bf(u.x); v1 = f2bf(u.y); v2 = f2bf(u.z); v3 = f2bf(u.w);
            }
            int k, n, k8;
            if (b <= 1) { k = i >> 5; n = (i & 31) * 4; k8 = (b == 1 ? 8 : 0) + (k >> 3); }
            else        { k = i >> 4; n = (i & 15) * 4; k8 = k >> 3; }
            int kc = k8 >> 2, q = k8 & 3, w = k & 7;
            int basei = ((n >> 4) * 4 + kc) * 512 + (q * 16 + (n & 15)) * 8 + w;
            dst[basei] = v0; dst[basei + 8] = v1; dst[basei + 16] = v2; dst[basei + 24] = v3;
        }
    } else {
        // ---- probe role: flags for layer kernels ----
        int a = tid >> 5, lane = tid & 31;
        if (tid < 8) sh[tid] = 0;
        __syncthreads();
        if (a < 7) {
            const void* ptrs[7] = {x, W1l, W1r, b1, W2l, W2r, b2};
            int cs[7] = {c0, c1, c2, c3, c4, c5, c6};
            int C = cs[a];
            int stride = C / 32; if (stride < 1) stride = 1;
            long long i = (long long)lane * stride;
            if (i > C - 1) i = C - 1;
            i &= ~1LL;
            u16 v = ((const u16*)ptrs[a])[i];
            int e = (v >> 7) & 0xFF;
            int sane = ((e >= 0x50 && e <= 0x97) || v == 0) ? 1 : 0;
            atomicAdd(&sh[a], sane);
        } else if (a == 7) {
            long long n32 = 2LL * ne;
            long long stride = n32 / 32; if (stride < 1) stride = 1;
            long long i = (long long)lane * stride; i |= 1;
            if (i >= n32) i = 1;
            int wv = ((const int*)ei)[i];
            atomicAdd(&sh[7], wv != 0 ? 1 : 0);
        }
        __syncthreads();
        if (tid < 7) flags[tid] = (sh[tid] >= 24) ? 1 : 0;
        if (tid == 7) flags[7] = (sh[7] == 0) ? 1 : 0;
    }
}

// ---------------- per-bucket scan over chunks ----------------
__global__ __launch_bounds__(256) void scan2d(
    const int* __restrict__ hist2d, int* __restrict__ base2d,
    int* __restrict__ btot, int nchunk) {
    __shared__ int t0[256];
    int b = blockIdx.x, tid = threadIdx.x;
    int v = (tid < nchunk) ? hist2d[b * NCP + tid] : 0;
    t0[tid] = v;
    __syncthreads();
    for (int d = 1; d < 256; d <<= 1) {
        int t = (tid >= d) ? t0[tid - d] : 0;
        __syncthreads();
        t0[tid] += t;
        __syncthreads();
    }
    if (tid < nchunk) base2d[b * NCP + tid] = t0[tid] - v;
    if (tid == 255) btot[b] = t0[255];
}

// ---------------- partition: bucket-grouped packed edges, atomic-free -----
// bucket-offset scan (old scan_buckets) inlined; e64 detected inline.
__global__ __launch_bounds__(512) void partition_k(
    const void* __restrict__ ei, const int* __restrict__ btot,
    const int* __restrict__ base2d,
    unsigned* __restrict__ ep, int nn, int ne, int nb) {
    __shared__ unsigned stage[CHUNK];    // 32 KB
    __shared__ u16 ab[CHUNK];            // 16 KB
    __shared__ int hist[512], incl[512], exl[512], gbase[512], lcur[512];
    __shared__ int e64s;
    int tid = threadIdx.x;
    int base = blockIdx.x * CHUNK;
    hist[tid] = 0;
    int samp = 0;
    if (tid < 32) {
        long long n32 = 2LL * ne;
        long long stride = n32 / 32; if (stride < 1) stride = 1;
        long long i = (long long)tid * stride; i |= 1;
        if (i >= n32) i = 1;
        samp = (((const int*)ei)[i] != 0);
    }
    unsigned long long bm = __ballot(samp);
    if (tid == 0) e64s = (bm == 0ULL) ? 1 : 0;
    __syncthreads();
    int e64 = e64s;
    unsigned pk[16]; int bk[16];
#pragma unroll
    for (int j = 0; j < 16; j++) {
        int e = base + j * 512 + tid;
        bk[j] = -1;
        pk[j] = 0;
        if (e < ne) {
            int src, dst;
            if (e64) {
                src = (int)((const long long*)ei)[e];
                dst = (int)((const long long*)ei)[(size_t)ne + e];
            } else {
                src = ((const int*)ei)[e];
                dst = ((const int*)ei)[(size_t)ne + e];
            }
            if ((unsigned)dst < (unsigned)nn) {
                if ((unsigned)src >= (unsigned)nn) src = 0;
                bk[j] = dst >> BSHIFT;
                pk[j] = (unsigned)src | ((unsigned)(dst & (BSIZE - 1)) << 17);
                atomicAdd(&hist[bk[j]], 1);
            }
        }
    }
    __syncthreads();
    incl[tid] = hist[tid];
    __syncthreads();
    for (int d = 1; d < 512; d <<= 1) {
        int t = (tid >= d) ? incl[tid - d] : 0;
        __syncthreads();
        incl[tid] += t;
        __syncthreads();
    }
    int ex = incl[tid] - hist[tid];
    exl[tid] = ex;
    lcur[tid] = ex;
    int tot = incl[511];
    __syncthreads();
    // inline bucket-offset scan over btot (reuse incl)
    incl[tid] = (tid < nb) ? btot[tid] : 0;
    __syncthreads();
    for (int d = 1; d < 512; d <<= 1) {
        int t = (tid >= d) ? incl[tid - d] : 0;
        __syncthreads();
        incl[tid] += t;
        __syncthreads();
    }
    int bo_t = incl[tid] - ((tid < nb) ? btot[tid] : 0);
    gbase[tid] = (tid < nb) ? (bo_t + base2d[tid * NCP + blockIdx.x]) : 0;
    __syncthreads();
#pragma unroll
    for (int j = 0; j < 16; j++) {
        if (bk[j] >= 0) {
            int r = atomicAdd(&lcur[bk[j]], 1);
            stage[r] = pk[j];
            ab[r] = (u16)bk[j];
        }
    }
    __syncthreads();
    for (int j = tid; j < tot; j += 512) {
        int b = ab[j];
        ep[gbase[b] + (j - exl[b])] = stage[j];
    }
}

// ---------------- per-bucket CSR finalize (bucket scan inlined) ----------
__global__ __launch_bounds__(512) void csr_fill2(
    const unsigned* __restrict__ ep, const int* __restrict__ btot,
    int* __restrict__ off, int* __restrict__ cnt, int* __restrict__ esrc,
    int nn, int nb) {
    __shared__ int hist[BSIZE], incl[BSIZE], lcur[BSIZE];
    int b = blockIdx.x;
    int tid = threadIdx.x;
    // bucket-offset scan
    incl[tid] = (tid < nb) ? btot[tid] : 0;
    __syncthreads();
    for (int d = 1; d < 512; d <<= 1) {
        int t = (tid >= d) ? incl[tid - d] : 0;
        __syncthreads();
        incl[tid] += t;
        __syncthreads();
    }
    int end = incl[b];
    int beg = end - btot[b];
    __syncthreads();
    hist[tid] = 0;
    __syncthreads();
    for (int j = beg + tid; j < end; j += 512)
        atomicAdd(&hist[(ep[j] >> 17) & (BSIZE - 1)], 1);
    __syncthreads();
    incl[tid] = hist[tid];
    __syncthreads();
    for (int d = 1; d < 512; d <<= 1) {
        int t = (tid >= d) ? incl[tid - d] : 0;
        __syncthreads();
        incl[tid] += t;
        __syncthreads();
    }
    int ex = beg + incl[tid] - hist[tid];
    lcur[tid] = ex;
    int node = b * BSIZE + tid;
    if (node < nn) { off[node] = ex; cnt[node] = hist[tid]; }
    __syncthreads();
    for (int j = beg + tid; j < end; j += 512) {
        unsigned p = ep[j];
        int r = atomicAdd(&lcur[(p >> 17) & (BSIZE - 1)], 1);
        esrc[r] = (int)(p & 0x1FFFFu);
    }
}

// ---------------- layer 1 (+ fused pre2 when gpt != null) ----------------
// 512 thr = 32 nodes x 16 lanes (gather) = 8 waves (MFMA).
// Tile M=32,N=128,K=128. A (gather result) in fragment-major LDS (8KB);
// B read directly from packed global wpk (L2-resident).
// Fused tail: stage h-tile (bf16) fragment-major back into wA, 4 MFMAs/wave
// against W2l -> g[32x64] stored to global.
__global__ __launch_bounds__(512, 8) void layer1(
    const void* __restrict__ x, const u16* __restrict__ xb,
    const int* __restrict__ esrc,
    const int* __restrict__ off, const int* __restrict__ cnt,
    const u16* __restrict__ w1g, const u16* __restrict__ w2lg,
    const void* __restrict__ b1,
    u16* __restrict__ h, u16* __restrict__ gpt,
    const int* __restrict__ flags, int nn) {
    __shared__ __align__(16) u16 wA[8 * 512];    // 8 KB,  chunks (mtile*4+kc)
    __shared__ float b_s[128];
    int tid = threadIdx.x;
    int node0 = blockIdx.x * 32;

    if (tid < 128) b_s[tid] = flags[3] ? bf2f(((const u16*)b1)[tid]) : ((const float*)b1)[tid];

    int grp = tid >> 4, gl = tid & 15;
    int n = node0 + grp;
    int mtile = grp >> 4, l15m = grp & 15;
    int idx_mean = (mtile * 4 + (gl >> 3)) * 512 + (((gl >> 1) & 3) * 16 + l15m) * 8 + (gl & 1) * 4;
    int idx_x = (mtile * 4 + 2 + (gl >> 3)) * 512 + (((gl >> 1) & 3) * 16 + l15m) * 8 + (gl & 1) * 4;
    const u16* xs = flags[0] ? (const u16*)x : xb;
    if (n < nn) {
        int beg = off[n], deg = cnt[n];
        float a0 = 0.f, a1 = 0.f, a2 = 0.f, a3 = 0.f;
        int i = 0;
        const u16* xbp = xs + gl * 4;
        for (; i + 16 <= deg; i += 16) {
            ushort4 v[16];
#pragma unroll
            for (int j = 0; j < 16; j++) {
                int s0 = esrc[beg + i + j];
                v[j] = *(const ushort4*)(xbp + (size_t)s0 * 64);
            }
#pragma unroll
            for (int j = 0; j < 16; j++) {
                a0 += bf2f(v[j].x); a1 += bf2f(v[j].y);
                a2 += bf2f(v[j].z); a3 += bf2f(v[j].w);
            }
        }
        for (; i + 8 <= deg; i += 8) {
            ushort4 v[8];
#pragma unroll
            for (int j = 0; j < 8; j++) {
                int s0 = esrc[beg + i + j];
                v[j] = *(const ushort4*)(xbp + (size_t)s0 * 64);
            }
#pragma unroll
            for (int j = 0; j < 8; j++) {
                a0 += bf2f(v[j].x); a1 += bf2f(v[j].y);
                a2 += bf2f(v[j].z); a3 += bf2f(v[j].w);
            }
        }
        for (; i < deg; i++) {
            int s0 = esrc[beg + i];
            ushort4 v = *(const ushort4*)(xbp + (size_t)s0 * 64);
            a0 += bf2f(v.x); a1 += bf2f(v.y); a2 += bf2f(v.z); a3 += bf2f(v.w);
        }
        float inv = 1.0f / (float)(deg > 0 ? deg : 1);
        *(ushort4*)&wA[idx_mean] =
            make_ushort4(f2bf(a0 * inv), f2bf(a1 * inv), f2bf(a2 * inv), f2bf(a3 * inv));
        *(ushort4*)&wA[idx_x] = *(const ushort4*)(xs + (size_t)n * 64 + gl * 4);
    } else {
        *(ushort4*)&wA[idx_mean] = make_ushort4(0, 0, 0, 0);
        *(ushort4*)&wA[idx_x] = make_ushort4(0, 0, 0, 0);
    }
    __syncthreads();

    int wv = tid >> 6, lane = tid & 63;
    int l15 = lane & 15, q = lane >> 4;
    f32x4 acc0 = {0.f, 0.f, 0.f, 0.f};
    f32x4 acc1 = {0.f, 0.f, 0.f, 0.f};
#pragma unroll
    for (int kc = 0; kc < 4; kc++) {
        short8 a0 = *(const short8*)&wA[(kc) * 512 + lane * 8];
        short8 a1 = *(const short8*)&wA[(4 + kc) * 512 + lane * 8];
        short8 b  = *(const short8*)&w1g[(wv * 4 + kc) * 512 + lane * 8];
        acc0 = __builtin_amdgcn_mfma_f32_16x16x32_bf16(a0, b, acc0, 0, 0, 0);
        acc1 = __builtin_amdgcn_mfma_f32_16x16x32_bf16(a1, b, acc1, 0, 0, 0);
    }
    int nc = wv * 16 + l15;
    float bias = b_s[nc];
    u16 hv0[4], hv1[4];
#pragma unroll
    for (int r = 0; r < 4; r++) {
        hv0[r] = f2bf(fmaxf(acc0[r] + bias, 0.0f));
        hv1[r] = f2bf(fmaxf(acc1[r] + bias, 0.0f));
        int m = q * 4 + r;
        int nd = node0 + m;
        if (nd < nn) h[(size_t)nd * 128 + nc] = hv0[r];
        nd = node0 + 16 + m;
        if (nd < nn) h[(size_t)nd * 128 + nc] = hv1[r];
    }
    if (gpt) {
        // ---- fused pre2: g = relu(h) @ W2_l for this block's 32 rows ----
        __syncthreads();                       // all waves done reading wA
        // h element (row m, col nc): A-frag addr chunk=(m>=16?4:0)+ (nc>>5),
        // pos = (((nc&31)>>3)*16 + (m&15))*8 + (nc&7)
        int kcg = wv >> 1;                     // nc>>5
        int qg  = ((wv & 1) << 1) | (l15 >> 3);
        int wg  = l15 & 7;
#pragma unroll
        for (int r = 0; r < 4; r++) {
            int m = q * 4 + r;
            wA[kcg * 512 + (qg * 16 + m) * 8 + wg]       = hv0[r];
            wA[(4 + kcg) * 512 + (qg * 16 + m) * 8 + wg] = hv1[r];
        }
        __syncthreads();
        int mt2 = wv >> 2, nt2 = wv & 3;
        f32x4 ag = {0.f, 0.f, 0.f, 0.f};
#pragma unroll
        for (int kc = 0; kc < 4; kc++) {
            short8 a = *(const short8*)&wA[(mt2 * 4 + kc) * 512 + lane * 8];
            short8 b = *(const short8*)&w2lg[(nt2 * 4 + kc) * 512 + lane * 8];
            ag = __builtin_amdgcn_mfma_f32_16x16x32_bf16(a, b, ag, 0, 0, 0);
        }
        int nc2 = nt2 * 16 + l15;
#pragma unroll
        for (int r = 0; r < 4; r++) {
            int nd = node0 + mt2 * 16 + q * 4 + r;
            if (nd < nn) gpt[(size_t)nd * 64 + nc2] = f2bf(ag[r]);
        }
    }
}

// ---------------- pre2 (fallback when ws too small for fused g) ----------
__global__ __launch_bounds__(256, 8) void pre2(
    const u16* __restrict__ h, const u16* __restrict__ w2lg,
    u16* __restrict__ g, int nn) {
    int tid = threadIdx.x;
    int node0 = blockIdx.x * 64;
    int wv = tid >> 6, lane = tid & 63;
    int l15 = lane & 15, q = lane >> 4;
    int arow = node0 + wv * 16 + l15;
    if (arow >= nn) arow = nn - 1;               // clamp; stores are guarded
    const u16* hrow = h + (size_t)arow * 128 + q * 8;
    f32x4 acc[4];
#pragma unroll
    for (int nt = 0; nt < 4; nt++) acc[nt] = (f32x4){0.f, 0.f, 0.f, 0.f};
#pragma unroll
    for (int kc = 0; kc < 4; kc++) {
        short8 a = *(const short8*)(hrow + kc * 32);
#pragma unroll
        for (int nt = 0; nt < 4; nt++) {
            short8 b = *(const short8*)&w2lg[(nt * 4 + kc) * 512 + lane * 8];
            acc[nt] = __builtin_amdgcn_mfma_f32_16x16x32_bf16(a, b, acc[nt], 0, 0, 0);
        }
    }
#pragma unroll
    for (int nt = 0; nt < 4; nt++) {
        int nc = nt * 16 + l15;
#pragma unroll
        for (int r = 0; r < 4; r++) {
            int nd = node0 + wv * 16 + q * 4 + r;
            if (nd < nn) g[(size_t)nd * 64 + nc] = f2bf(acc[nt][r]);
        }
    }
}

// ---------------- layer 2 ----------------
// out = mean(g[src]) + h @ W2_r + b2.
// Gather reads 128B g-rows; self-term MFMA M=32,N=64,K=128; B from global.
__global__ __launch_bounds__(512, 8) void layer2(
    const u16* __restrict__ h, const u16* __restrict__ g,
    const int* __restrict__ esrc,
    const int* __restrict__ off, const int* __restrict__ cnt,
    const u16* __restrict__ w2rg, const void* __restrict__ b2,
    void* __restrict__ out, const int* __restrict__ flags, int nn) {
    __shared__ __align__(16) u16 wA2[8 * 512];       // 8 KB,  (mtile*4+kc)
    __shared__ __align__(16) float meanbuf[32][72];  // 9 KB (stride 72)
    __shared__ float b_s[64];
    int tid = threadIdx.x;
    int node0 = blockIdx.x * 32;
    int obf = flags[0];

    if (tid < 64) b_s[tid] = flags[6] ? bf2f(((const u16*)b2)[tid]) : ((const float*)b2)[tid];

    int grp = tid >> 4, gl = tid & 15;
    int n = node0 + grp;
    int mtile = grp >> 4, m15 = grp & 15;
    int idx_h = (mtile * 4 + (gl >> 2)) * 512 + ((gl & 3) * 16 + m15) * 8;
    if (n < nn) {
        // stage self row h[n] into fragment-major LDS
        *(uint4*)&wA2[idx_h] = *(const uint4*)(h + (size_t)n * 128 + gl * 8);
        // gather-mean of g rows (64 bf16 = 128B; this lane covers cols gl*4..+3)
        int beg = off[n], deg = cnt[n];
        float a0 = 0.f, a1 = 0.f, a2 = 0.f, a3 = 0.f;
        const u16* gb = g + gl * 4;
        int i = 0;
        for (; i + 16 <= deg; i += 16) {
            uint2 v[16];
#pragma unroll
            for (int j = 0; j < 16; j++) {
                int s0 = esrc[beg + i + j];
                v[j] = *(const uint2*)(gb + (size_t)s0 * 64);
            }
#pragma unroll
            for (int j = 0; j < 16; j++) {
                a0 += bfu_lo(v[j].x); a1 += bfu_hi(v[j].x);
                a2 += bfu_lo(v[j].y); a3 += bfu_hi(v[j].y);
            }
        }
        for (; i + 8 <= deg; i += 8) {
            uint2 v[8];
#pragma unroll
            for (int j = 0; j < 8; j++) {
                int s0 = esrc[beg + i + j];
                v[j] = *(const uint2*)(gb + (size_t)s0 * 64);
            }
#pragma unroll
            for (int j = 0; j < 8; j++) {
                a0 += bfu_lo(v[j].x); a1 += bfu_hi(v[j].x);
                a2 += bfu_lo(v[j].y); a3 += bfu_hi(v[j].y);
            }
        }
        for (; i < deg; i++) {
            int s0 = esrc[beg + i];
            uint2 v = *(const uint2*)(gb + (size_t)s0 * 64);
            a0 += bfu_lo(v.x); a1 += bfu_hi(v.x);
            a2 += bfu_lo(v.y); a3 += bfu_hi(v.y);
        }
        float inv = 1.0f / (float)(deg > 0 ? deg : 1);
        *(float4*)&meanbuf[grp][gl * 4] =
            make_float4(a0 * inv, a1 * inv, a2 * inv, a3 * inv);
    } else {
        *(uint4*)&wA2[idx_h] = make_uint4(0, 0, 0, 0);
        *(float4*)&meanbuf[grp][gl * 4] = make_float4(0.f, 0.f, 0.f, 0.f);
    }
    __syncthreads();

    int wv = tid >> 6, lane = tid & 63;
    int l15 = lane & 15, q = lane >> 4;
    int mt = wv >> 2, nt = wv & 3;
    f32x4 acc = {0.f, 0.f, 0.f, 0.f};
#pragma unroll
    for (int kc = 0; kc < 4; kc++) {
        short8 a = *(const short8*)&wA2[(mt * 4 + kc) * 512 + lane * 8];
        short8 b = *(const short8*)&w2rg[(nt * 4 + kc) * 512 + lane * 8];
        acc = __builtin_amdgcn_mfma_f32_16x16x32_bf16(a, b, acc, 0, 0, 0);
    }
    int nc = nt * 16 + l15;
    float bias = b_s[nc];
#pragma unroll
    for (int r = 0; r < 4; r++) {
        int m = mt * 16 + q * 4 + r;
        int nd = node0 + m;
        if (nd < nn) {
            float v = acc[r] + bias + meanbuf[m][nc];
            if (obf) ((u16*)out)[(size_t)nd * 64 + nc] = f2bf(v);
            else     ((float*)out)[(size_t)nd * 64 + nc] = v;
        }
    }
}

// ---------------- fallback ----------------
__global__ __launch_bounds__(256) void zero_out_k(u16* __restrict__ out, int n) {
    int i = blockIdx.x * 256 + threadIdx.x;
    if (i < n) out[i] = 0;
}

extern "C" void kernel_launch(void* const* d_in, const int* in_sizes, int n_in,
                              void* d_out, int out_size, void* d_ws, size_t ws_size,
                              hipStream_t stream) {
    const void* x   = d_in[0];
    const void* ei  = d_in[1];
    const void* W1l = d_in[2];
    const void* W1r = d_in[3];
    const void* b1  = d_in[4];
    const void* W2l = d_in[5];
    const void* W2r = d_in[6];
    const void* b2  = d_in[7];

    int nn = in_sizes[0] / 64;
    int ne = in_sizes[1] / 2;
    int nb = (nn + BSIZE - 1) / BSIZE;
    int nchunk = (ne + CHUNK - 1) / CHUNK;

    auto al = [](size_t v) { return (v + 255) & ~(size_t)255; };
    size_t o_flags = 0;
    size_t o_btot  = 256;                              // 512 ints
    size_t o_wpk   = al(o_btot + 512 * 4);             // 64 KB packed weights
    size_t o_cnt   = al(o_wpk + 65536);
    size_t o_off   = al(o_cnt + (size_t)nn * 4);
    size_t o_esrc  = al(o_off + (size_t)nn * 4);
    size_t o_h     = al(o_esrc + (size_t)ne * 4);
    size_t o_xb    = al(o_h + (size_t)nn * 128 * 2);   // xb (also g in fallback)
    size_t ws_base = o_xb + (size_t)nn * 64 * 2;
    size_t o_g2    = al(ws_base);                      // dedicated g (fused path)
    size_t ws_fused = o_g2 + (size_t)nn * 64 * 2;

    // overlays inside the h region (all dead before layer1 writes h):
    size_t o_ep   = o_h;                               // ne*4 B
    size_t o_h2d  = al(o_ep + (size_t)ne * 4);         // nb*NCP*4
    size_t o_b2d  = al(o_h2d + (size_t)512 * NCP * 4); // nb*NCP*4
    size_t ov_end = o_b2d + (size_t)512 * NCP * 4;

    bool ok = ws_size >= ws_base && nb >= 1 && nb <= 512 && nn <= 131072 &&
              nchunk <= NCP && ov_end <= o_xb;
    if (!ok) {
        zero_out_k<<<(out_size + 255) / 256, 256, 0, stream>>>((u16*)d_out, out_size);
        return;
    }
    bool fused = ws_size >= ws_fused;

    char* ws = (char*)d_ws;
    int* flags  = (int*)(ws + o_flags);
    int* btot   = (int*)(ws + o_btot);
    u16* wpk    = (u16*)(ws + o_wpk);
    int* cnt    = (int*)(ws + o_cnt);
    int* off    = (int*)(ws + o_off);
    int* esrc   = (int*)(ws + o_esrc);
    u16* h      = (u16*)(ws + o_h);
    u16* xb     = (u16*)(ws + o_xb);                   // xb (g overlay in fallback)
    u16* gbuf   = fused ? (u16*)(ws + o_g2) : xb;
    unsigned* ep = (unsigned*)(ws + o_ep);
    int* hist2d = (int*)(ws + o_h2d);
    int* base2d = (int*)(ws + o_b2d);

    int ncvt = (nn * 16 + 511) / 512;
    setup_k<<<nchunk + ncvt + 5, 512, 0, stream>>>(
        x, ei, W1l, W1r, b1, W2l, W2r, b2, wpk, xb, hist2d, flags,
        nn, ne, nb, nchunk, ncvt,
        in_sizes[0], in_sizes[2], in_sizes[3], in_sizes[4],
        in_sizes[5], in_sizes[6], in_sizes[7]);
    scan2d<<<nb, 256, 0, stream>>>(hist2d, base2d, btot, nchunk);
    partition_k<<<nchunk, 512, 0, stream>>>(ei, btot, base2d, ep, nn, ne, nb);
    csr_fill2<<<nb, 512, 0, stream>>>(ep, btot, off, cnt, esrc, nn, nb);
    int lb = (nn + 31) / 32;
    layer1<<<lb, 512, 0, stream>>>(x, xb, esrc, off, cnt, wpk, wpk + 16384, b1,
                                   h, fused ? gbuf : (u16*)nullptr, flags, nn);
    if (!fused)
        pre2<<<(nn + 63) / 64, 256, 0, stream>>>(h, wpk + 16384, gbuf, nn);
    layer2<<<lb, 512, 0, stream>>>(h, gbuf, esrc, off, cnt, wpk + 24576, b2,
                                   d_out, flags, nn);
}